// Round 7
// baseline (168.330 us; speedup 1.0000x reference)
//
#include <hip/hip_runtime.h>
#include <hip/hip_bf16.h>

#define B_ROWS 4096
#define TWOB   8192
#define DIM    256
#define INV_T  14.285714285714286f   // 1/0.07
#define EXPSCALE 20.609865074705232f // (1/0.07) * log2(e) -> use exp2f

#define BM 128
#define BN 128
#define NSTRIP 16
#define CT_PER_STRIP 4    // (8192/128)/NSTRIP

typedef __bf16 bf16x8 __attribute__((ext_vector_type(8)));   // 16 bytes
typedef float  f32x4  __attribute__((ext_vector_type(4)));

// ---------------- kernel 1: row L2-normalize, fp32 -> bf16 ----------------
// Also zeroes the finalize accumulators (ws is re-poisoned 0xAA before every launch).
__global__ __launch_bounds__(256) void normalize_k(const float* __restrict__ zi,
                                                   const float* __restrict__ zj,
                                                   unsigned short* __restrict__ zn,
                                                   float* __restrict__ loss_acc,
                                                   unsigned int* __restrict__ counter) {
    if (blockIdx.x == 0 && threadIdx.x == 0) {
        loss_acc[0] = 0.0f;
        counter[0]  = 0u;
    }
    int wave = threadIdx.x >> 6;
    int lane = threadIdx.x & 63;
    int row  = blockIdx.x * 4 + wave;             // 2048 blocks * 4 waves = 8192 rows
    const float* src = (row < B_ROWS) ? (zi + (size_t)row * DIM)
                                      : (zj + (size_t)(row - B_ROWS) * DIM);
    float4 v = reinterpret_cast<const float4*>(src)[lane];   // 64 lanes * 4 = 256
    float ss = v.x * v.x + v.y * v.y + v.z * v.z + v.w * v.w;
#pragma unroll
    for (int off = 32; off >= 1; off >>= 1) ss += __shfl_xor(ss, off);
    float norm = sqrtf(ss);
    norm = fmaxf(norm, 1e-8f);                    // COS_EPS
    float inv = 1.0f / norm;
    ushort4 o;
    o.x = __builtin_bit_cast(unsigned short, __float2bfloat16(v.x * inv));
    o.y = __builtin_bit_cast(unsigned short, __float2bfloat16(v.y * inv));
    o.z = __builtin_bit_cast(unsigned short, __float2bfloat16(v.z * inv));
    o.w = __builtin_bit_cast(unsigned short, __float2bfloat16(v.w * inv));
    reinterpret_cast<ushort4*>(zn)[(size_t)row * 64 + lane] = o;   // ushort4 = 8 B granule
}

// ---------------- kernel 2: flash NT-Xent main, LDS-FREE ----------------
// zn is 4 MB -> fully L2-resident. The 16x16x32 bf16 A/B fragment layout
// (m = lc, k = quad*8+j) is a 64B-coalesced direct global load: lane reads
// 16 B at element (row*256 + kt*32 + quad*8). NO LDS staging, NO K-loop
// barriers, NO bank conflicts. Waves run free; 1-deep register prefetch
// (next kt issued before current kt's 16 MFMAs; next ct's kt0 issued before
// the exp epilogue) + ~3 blocks/CU cover L1/L2 latency.
// BUGFIX R6: fragment pointer must be a 16-BYTE type. R6 used ushort4* (8 B)
// with 16-B granule indices -> every load at half the intended offset ->
// plausible-but-wrong loss (absmax 0.31). znv is now bf16x8* (16 B).
__global__ __launch_bounds__(256) void ntxent_main(const unsigned short* __restrict__ znu,
                                                   float* __restrict__ pos,
                                                   float* __restrict__ strip_sums) {
    const bf16x8* __restrict__ znv = (const bf16x8*)znu;  // 16B granules: idx = row*32 + k/8
    __shared__ float rowsumL[2][BM];              // 1 KB, final reduce only

    const int tid  = threadIdx.x;
    const int wave = tid >> 6;
    const int lane = tid & 63;
    const int wr = wave >> 1, wc = wave & 1;
    const int quad = lane >> 4, lc = lane & 15;
    const int rt    = blockIdx.x;        // row-tile 0..63
    const int strip = blockIdx.y;        // 0..NSTRIP-1
    const int row0  = rt * BM;
    const int posTile = (rt + 32) & 63;  // col-tile holding (row+4096) mod 8192

    // per-lane fragment base indices (16B granules); kt adds +kt*4 (= 64 B)
    const int arow = row0 + wr * 64 + lc;
    int aidx[4], bidx[4];
#pragma unroll
    for (int mi = 0; mi < 4; ++mi) aidx[mi] = (arow + mi * 16) * 32 + quad;
    {
        const int brow = strip * CT_PER_STRIP * BN + wc * 64 + lc;
#pragma unroll
        for (int ni = 0; ni < 4; ++ni) bidx[ni] = (brow + ni * 16) * 32 + quad;
    }

    f32x4 acc[4][4];
    float rsum[4][4];
#pragma unroll
    for (int mi = 0; mi < 4; ++mi)
#pragma unroll
        for (int r = 0; r < 4; ++r) rsum[mi][r] = 0.0f;

    // prologue: load (ct=0, kt=0) fragments
    bf16x8 a_cur[4], b_cur[4];
#pragma unroll
    for (int mi = 0; mi < 4; ++mi) a_cur[mi] = znv[aidx[mi]];
#pragma unroll
    for (int ni = 0; ni < 4; ++ni) b_cur[ni] = znv[bidx[ni]];

    for (int ct = 0; ct < CT_PER_STRIP; ++ct) {
        const int colTile = strip * CT_PER_STRIP + ct;
        const int col0 = colTile * BN;
#pragma unroll
        for (int mi = 0; mi < 4; ++mi)
#pragma unroll
            for (int ni = 0; ni < 4; ++ni) acc[mi][ni] = f32x4{0.f, 0.f, 0.f, 0.f};

#pragma unroll
        for (int kt = 0; kt < 8; ++kt) {
            bf16x8 a_nxt[4], b_nxt[4];
            if (kt < 7) {
                // prefetch next kt of this ct
#pragma unroll
                for (int mi = 0; mi < 4; ++mi)
                    a_nxt[mi] = znv[aidx[mi] + (kt + 1) * 4];
#pragma unroll
                for (int ni = 0; ni < 4; ++ni)
                    b_nxt[ni] = znv[bidx[ni] + (kt + 1) * 4];
            } else {
                // prefetch next ct's kt=0 (issued BEFORE the exp epilogue, which
                // then covers its latency). Last ct: reload current (discarded).
                const int badd = (ct < CT_PER_STRIP - 1) ? BN * 32 : 0;
#pragma unroll
                for (int mi = 0; mi < 4; ++mi)
                    a_nxt[mi] = znv[aidx[mi]];
#pragma unroll
                for (int ni = 0; ni < 4; ++ni) {
                    bidx[ni] += badd;
                    b_nxt[ni] = znv[bidx[ni]];
                }
            }
#pragma unroll
            for (int mi = 0; mi < 4; ++mi)
#pragma unroll
                for (int ni = 0; ni < 4; ++ni)
                    acc[mi][ni] = __builtin_amdgcn_mfma_f32_16x16x32_bf16(
                        a_cur[mi], b_cur[ni], acc[mi][ni], 0, 0, 0);
#pragma unroll
            for (int x = 0; x < 4; ++x) { a_cur[x] = a_nxt[x]; b_cur[x] = b_nxt[x]; }
        }

        // epilogue: exp + running row sums (C/D layout: row = quad*4+reg, col = lc).
        // Runs while next ct's kt0 fragment loads are in flight.
        const bool special = (colTile == rt) || (colTile == posTile);
#pragma unroll
        for (int mi = 0; mi < 4; ++mi) {
#pragma unroll
            for (int ni = 0; ni < 4; ++ni) {
                f32x4 a = acc[mi][ni];
#pragma unroll
                for (int r = 0; r < 4; ++r) {
                    float e = exp2f(a[r] * EXPSCALE);   // exp(s/T), one mul + v_exp
                    if (special) {
                        int gr = row0 + wr * 64 + mi * 16 + quad * 4 + r;
                        int gc = col0 + wc * 64 + ni * 16 + lc;
                        if (gc == ((gr + B_ROWS) & (TWOB - 1))) pos[gr] = a[r] * INV_T;
                        if (gr == gc) e = 0.0f;          // diagonal mask
                    }
                    rsum[mi][r] += e;
                }
            }
        }
    }

    // cross-lane: sum the 16 columns (low 4 lane bits) holding each row
#pragma unroll
    for (int mi = 0; mi < 4; ++mi) {
#pragma unroll
        for (int r = 0; r < 4; ++r) {
            float v = rsum[mi][r];
            v += __shfl_xor(v, 1);
            v += __shfl_xor(v, 2);
            v += __shfl_xor(v, 4);
            v += __shfl_xor(v, 8);
            if (lc == 0) rowsumL[wc][wr * 64 + mi * 16 + quad * 4 + r] = v;
        }
    }
    __syncthreads();
    if (tid < BM)
        strip_sums[(size_t)strip * TWOB + row0 + tid] = rowsumL[0][tid] + rowsumL[1][tid];
}

// ---------------- kernel 3: loss = mean(log(sumexp) - pos) ----------------
// 32 blocks x 256 threads, one row per thread. Device-scope atomic accumulation;
// last block to finish writes the mean. Accumulators zeroed by normalize_k.
__global__ __launch_bounds__(256) void finalize_k(const float* __restrict__ strip_sums,
                                                  const float* __restrict__ pos,
                                                  float* __restrict__ loss_acc,
                                                  unsigned int* __restrict__ counter,
                                                  float* __restrict__ out) {
    __shared__ float wsums[4];
    const int tid = threadIdx.x;
    const int r   = blockIdx.x * 256 + tid;
    float s = 0.0f;
#pragma unroll
    for (int st = 0; st < NSTRIP; ++st) s += strip_sums[(size_t)st * TWOB + r];
    float local = logf(s) - pos[r];
#pragma unroll
    for (int off = 32; off >= 1; off >>= 1) local += __shfl_xor(local, off);
    if ((tid & 63) == 0) wsums[tid >> 6] = local;
    __syncthreads();
    if (tid == 0) {
        float bsum = wsums[0] + wsums[1] + wsums[2] + wsums[3];
        atomicAdd(loss_acc, bsum);
        __threadfence();                              // order loss add before counter add
        unsigned int done = atomicAdd(counter, 1u);
        if (done == gridDim.x - 1) {
            float total = atomicAdd(loss_acc, 0.0f);  // device-scope atomic read
            out[0] = total / (float)TWOB;
        }
    }
}

extern "C" void kernel_launch(void* const* d_in, const int* in_sizes, int n_in,
                              void* d_out, int out_size, void* d_ws, size_t ws_size,
                              hipStream_t stream) {
    const float* zi = (const float*)d_in[0];
    const float* zj = (const float*)d_in[1];
    // ws layout: zn (4 MB) | pos (32 KB) | strip_sums (512 KB) | loss_acc | counter
    unsigned short* zn = (unsigned short*)d_ws;
    float* pos        = (float*)((char*)d_ws + (size_t)TWOB * DIM * 2);
    float* strip_sums = pos + TWOB;
    float* loss_acc   = strip_sums + (size_t)NSTRIP * TWOB;
    unsigned int* counter = (unsigned int*)(loss_acc + 1);
    float* out = (float*)d_out;

    normalize_k<<<dim3(TWOB / 4), 256, 0, stream>>>(zi, zj, zn, loss_acc, counter);
    ntxent_main<<<dim3(64, NSTRIP), 256, 0, stream>>>(zn, pos, strip_sums);
    finalize_k<<<dim3(TWOB / 256), 256, 0, stream>>>(strip_sums, pos, loss_acc, counter, out);
}